// Round 17
// baseline (107.331 us; speedup 1.0000x reference)
//
#include <hip/hip_runtime.h>

#define NB 2
#define CCH 256
#define LL 4096
#define NGRP 16
#define NHD 4
#define CHD 64
#define QR 768   // 3*C rows of qkv
#define SPLIT 4

typedef __attribute__((ext_vector_type(8))) short short8;   // 8 x bf16
typedef __attribute__((ext_vector_type(4))) float f32x4;    // MFMA acc
typedef __attribute__((ext_vector_type(4))) unsigned int uint32x4;

// ---------------- workspace layout (floats) ----------------
#define OFF_GP 64
#define OFF_BP 4224
#define OFF_WQ 5824
#define OFF_WO 202432
#define OFF_QT 235200
#define OFF_KT 1283776
#define OFF_V  2332352
#define OFF_PO 3380928
#define OFF_L  7575232
#define OFF_XT OFF_PO
#define OFF_AT OFF_QT

#define KSCALE 0.1803368801111204f   // 0.125 * log2(e)

__device__ __forceinline__ unsigned short f2bf(float f) {
    unsigned int u = __builtin_bit_cast(unsigned int, f);
    u += 0x7fffu + ((u >> 16) & 1u);   // RNE
    return (unsigned short)(u >> 16);
}
__device__ __forceinline__ float bf2f(unsigned short s) {
    unsigned int u = ((unsigned int)s) << 16;
    return __builtin_bit_cast(float, u);
}
__device__ __forceinline__ unsigned int cvtpk(float lo, float hi) {
    unsigned int r;
    asm("v_cvt_pk_bf16_f32 %0, %1, %2" : "=v"(r) : "v"(lo), "v"(hi));
    return r;
}

// Build the PV B-fragment (one 32-s half) from two QK^T accumulators
// entirely in-register (cvt_pk + permlane32/16_swap). Proven R8-R16.
__device__ __forceinline__ short8 build_pf(const f32x4 s_lo, const f32x4 s_hi) {
    unsigned int a0 = cvtpk(s_lo[0], s_lo[1]);
    unsigned int b0 = cvtpk(s_hi[0], s_hi[1]);
    unsigned int a1 = cvtpk(s_lo[2], s_lo[3]);
    unsigned int b1 = cvtpk(s_hi[2], s_hi[3]);
    asm("v_permlane32_swap_b32 %0, %1" : "+v"(a0), "+v"(b0));
    asm("v_permlane16_swap_b32 %0, %1" : "+v"(a0), "+v"(b0));
    asm("v_permlane32_swap_b32 %0, %1" : "+v"(a1), "+v"(b1));
    asm("v_permlane16_swap_b32 %0, %1" : "+v"(a1), "+v"(b1));
    uint32x4 w = {a0, a1, b0, b1};
    return __builtin_bit_cast(short8, w);
}

// XOR-swizzled 64x256 bf16 LDS tile helpers (rows of 512B = 32 16B chunks).
__device__ __forceinline__ void stage_tile(unsigned short* lt,
                                           const unsigned short* src,
                                           int srcStride, int tid) {
    #pragma unroll
    for (int p = 0; p < 4; p++) {
        const int r  = p * 16 + (tid >> 4);
        const int cb = (tid & 15) * 2;
        const unsigned short* s = src + (size_t)r * srcStride + cb * 8;
        short8 a = *(const short8*)(s);
        short8 b = *(const short8*)(s + 8);
        char* d = (char*)lt + r * 512;
        *(short8*)(d + (((cb    ) ^ (r & 15)) << 4)) = a;
        *(short8*)(d + (((cb + 1) ^ (r & 15)) << 4)) = b;
    }
}
__device__ __forceinline__ short8 ldsfrag(const unsigned short* lt, int row, int ch) {
    return *(const short8*)((const char*)lt + row * 512 + ((ch ^ (row & 15)) << 4));
}

// ------- kernel 1: x -> xT bf16 [n][l][c] + group-norm partial sums -------
__global__ __launch_bounds__(256)
void k_xtgn(const float* __restrict__ x, unsigned short* __restrict__ xt,
            float* __restrict__ ws) {
    const int l0 = blockIdx.x * 64, c0 = blockIdx.y * 64, n = blockIdx.z;
    __shared__ __align__(16) unsigned short lt[64 * 64];
    __shared__ float red[2][4][4];
    const int tid = threadIdx.x;
    const int cl = tid >> 4;
    const int ll = (tid & 15) << 2;
    float s1[4], s2[4];
    #pragma unroll
    for (int cc = 0; cc < 4; cc++) {
        const int c = cl + cc * 16;
        float4 v = *(const float4*)(x + (size_t)(n * CCH + c0 + c) * LL + l0 + ll);
        s1[cc] = (v.x + v.y) + (v.z + v.w);
        s2[cc] = (v.x * v.x + v.y * v.y) + (v.z * v.z + v.w * v.w);
        const float vv[4] = {v.x, v.y, v.z, v.w};
        #pragma unroll
        for (int j = 0; j < 4; j++) {
            const int l = ll + j;
            const int byte = l * 128 + ((((c >> 3) ^ (l & 7)) << 4) | ((c & 7) * 2));
            *(unsigned short*)((char*)lt + byte) = f2bf(vv[j]);
        }
    }
    #pragma unroll
    for (int cc = 0; cc < 4; cc++)
        #pragma unroll
        for (int off = 32; off; off >>= 1) {
            s1[cc] += __shfl_down(s1[cc], off);
            s2[cc] += __shfl_down(s2[cc], off);
        }
    if ((tid & 63) == 0) {
        const int w = tid >> 6;
        #pragma unroll
        for (int cc = 0; cc < 4; cc++) { red[0][w][cc] = s1[cc]; red[1][w][cc] = s2[cc]; }
    }
    __syncthreads();
    if (tid < 4) {
        const float a = red[0][0][tid] + red[0][1][tid] + red[0][2][tid] + red[0][3][tid];
        const float b = red[1][0][tid] + red[1][1][tid] + red[1][2][tid] + red[1][3][tid];
        const int g = n * NGRP + (c0 >> 4) + tid;
        ws[OFF_GP + (g * 64 + blockIdx.x) * 2]     = a;
        ws[OFF_GP + (g * 64 + blockIdx.x) * 2 + 1] = b;
    }
    const int lr = tid >> 2;
    const int ch = (tid & 3) << 4;
    unsigned short* dst = xt + ((size_t)n * LL + l0 + lr) * CCH + c0 + ch;
    const int b0 = lr * 128 + ((((ch >> 3)    ) ^ (lr & 7)) << 4);
    const int b1 = lr * 128 + ((((ch >> 3) + 1) ^ (lr & 7)) << 4);
    *(short8*)dst       = *(const short8*)((char*)lt + b0);
    *(short8*)(dst + 8) = *(const short8*)((char*)lt + b1);
}

// stats-from-partials preamble
__device__ __forceinline__ void load_stats(const float* __restrict__ ws,
                                           float* smu, float* srs) {
    if (threadIdx.x < 32) {
        float s1 = 0.f, s2 = 0.f;
        #pragma unroll 8
        for (int i = 0; i < 64; i++) {
            s1 += ws[OFF_GP + (threadIdx.x * 64 + i) * 2];
            s2 += ws[OFF_GP + (threadIdx.x * 64 + i) * 2 + 1];
        }
        const float inv = 1.f / (float)(16 * LL);
        float m = s1 * inv;
        float var = s2 * inv - m * m;
        smu[threadIdx.x] = m;
        srs[threadIdx.x] = rsqrtf(var + 1e-6f);
    }
    __syncthreads();
}

// ------- kernel 2: fused weight conversion + effective bias ---------------
__global__ __launch_bounds__(256)
void k_bpw(const float* __restrict__ w_qkv, const float* __restrict__ w_out,
           const float* __restrict__ b_qkv, const float* __restrict__ gn_scale,
           const float* __restrict__ gn_bias, float* __restrict__ ws,
           unsigned short* __restrict__ wq, unsigned short* __restrict__ wo) {
    __shared__ float smu[32], srs[32];
    load_stats(ws, smu, srs);
    if (blockIdx.x < 448) {
        const int e = (blockIdx.x * 256 + threadIdx.x) * 4;
        if (e < NB * QR * CCH) {
            const int n = (e >= QR * CCH) ? 1 : 0;
            const int r = e - n * QR * CCH;
            const int o = r >> 8, c = r & 255;
            float4 w  = *(const float4*)(w_qkv + (size_t)o * CCH + c);
            float4 gs = *(const float4*)(gn_scale + c);
            const float rs = srs[n * NGRP + (c >> 4)];
            const float sc = (o < 256 ? KSCALE : 1.0f) * rs;
            ushort4 u;
            u.x = f2bf(w.x * gs.x * sc); u.y = f2bf(w.y * gs.y * sc);
            u.z = f2bf(w.z * gs.z * sc); u.w = f2bf(w.w * gs.w * sc);
            *(ushort4*)(wq + (size_t)n * QR * CCH + r) = u;
        } else {
            const int r = e - NB * QR * CCH;   // < 65536
            float4 w = *(const float4*)(w_out + r);
            ushort4 u;
            u.x = f2bf(w.x); u.y = f2bf(w.y); u.z = f2bf(w.z); u.w = f2bf(w.w);
            *(ushort4*)(wo + r) = u;
        }
    } else {
        const int oi = (blockIdx.x - 448) * 32 + (threadIdx.x >> 3);  // 0..1535
        const int j  = threadIdx.x & 7;
        const int n = (oi >= QR) ? 1 : 0;
        const int o = oi - n * QR;
        const float* wr = w_qkv + (size_t)o * CCH + j * 32;
        const float* gsr = gn_scale + j * 32;
        const float* gbr = gn_bias + j * 32;
        float s = 0.f;
        #pragma unroll
        for (int c = 0; c < 32; c += 4) {
            float4 w  = *(const float4*)(wr + c);
            float4 gs = *(const float4*)(gsr + c);
            float4 gb = *(const float4*)(gbr + c);
            const int gidx = n * NGRP + ((j * 32 + c) >> 4);
            const float mu = smu[gidx], rs = srs[gidx];
            s += w.x * (gb.x - mu * rs * gs.x) + w.y * (gb.y - mu * rs * gs.y)
               + w.z * (gb.z - mu * rs * gs.z) + w.w * (gb.w - mu * rs * gs.w);
        }
        s += __shfl_down(s, 4);
        s += __shfl_down(s, 2);
        s += __shfl_down(s, 1);
        if (j == 0) ws[OFF_BP + oi] = (b_qkv[o] + s) * (o < 256 ? KSCALE : 1.0f);
    }
}

// ------- kernel 3: QKV projection, bf16 MFMA, LDS-staged shared operand ---
// (R15 uniform version: 64l x 64o tiles; Q/K stage W, V stages xT.)
__global__ __launch_bounds__(256)
void k_qkv(const unsigned short* __restrict__ wq, const float* __restrict__ bp,
           const unsigned short* __restrict__ xt,
           unsigned short* __restrict__ qT, unsigned short* __restrict__ kT,
           unsigned short* __restrict__ vv) {
    const int l0 = blockIdx.x * 64, o0 = blockIdx.y * 64, n = blockIdx.z;
    const int tid = threadIdx.x, w = tid >> 6, r16 = tid & 15, g = (tid & 63) >> 4;
    __shared__ __align__(16) unsigned short lt[64 * 256];   // 32KB
    const unsigned short* xb = xt + (size_t)n * LL * CCH;
    const unsigned short* wb = wq + (size_t)n * QR * CCH;
    const bool isv = (o0 >= 512);

    stage_tile(lt, isv ? (xb + (size_t)l0 * CCH) : (wb + (size_t)o0 * CCH), CCH, tid);
    __syncthreads();

    f32x4 acc[4];
    #pragma unroll
    for (int i = 0; i < 4; i++) acc[i] = (f32x4){0.f, 0.f, 0.f, 0.f};

    if (!isv) {
        const unsigned short* xr = xb + (size_t)(l0 + w * 16 + r16) * CCH + g * 8;
        for (int kk = 0; kk < 8; kk++) {
            short8 xf = *(const short8*)(xr + kk * 32);
            #pragma unroll
            for (int af = 0; af < 4; af++) {
                short8 wf = ldsfrag(lt, af * 16 + r16, kk * 4 + g);
                acc[af] = __builtin_amdgcn_mfma_f32_16x16x32_bf16(wf, xf, acc[af], 0, 0, 0);
            }
        }
        const bool isq = (o0 < 256);
        const int h = (o0 >> 6) & 3;
        unsigned short* tb = (isq ? qT : kT) + ((size_t)n * NHD + h) * LL * CHD;
        const int t = l0 + w * 16 + r16;
        #pragma unroll
        for (int af = 0; af < 4; af++) {
            float4 bb = *(const float4*)(bp + n * QR + o0 + af * 16 + g * 4);
            ushort4 u;
            u.x = f2bf(acc[af][0] + bb.x); u.y = f2bf(acc[af][1] + bb.y);
            u.z = f2bf(acc[af][2] + bb.z); u.w = f2bf(acc[af][3] + bb.w);
            *(ushort4*)(tb + (size_t)t * CHD + af * 16 + g * 4) = u;
        }
    } else {
        const unsigned short* wr = wb + (size_t)(o0 + w * 16 + r16) * CCH + g * 8;
        for (int kk = 0; kk < 8; kk++) {
            short8 wf = *(const short8*)(wr + kk * 32);
            #pragma unroll
            for (int lb = 0; lb < 4; lb++) {
                short8 xf = ldsfrag(lt, lb * 16 + r16, kk * 4 + g);
                acc[lb] = __builtin_amdgcn_mfma_f32_16x16x32_bf16(xf, wf, acc[lb], 0, 0, 0);
            }
        }
        const int h = (o0 - 512) >> 6;
        const int o = o0 + w * 16 + r16;
        const float bb = bp[n * QR + o];
        unsigned short* vb = vv + ((size_t)n * NHD + h) * CHD * LL + (size_t)(o & 63) * LL;
        #pragma unroll
        for (int lb = 0; lb < 4; lb++) {
            ushort4 u;
            u.x = f2bf(acc[lb][0] + bb); u.y = f2bf(acc[lb][1] + bb);
            u.z = f2bf(acc[lb][2] + bb); u.w = f2bf(acc[lb][3] + bb);
            *(ushort4*)(vb + l0 + lb * 16 + g * 4) = u;
        }
    }
}

// ------- kernel 4: MFMA flash attention, ONE WAVE per block ---------------
// No LDS, no barriers, no lockstep: 2048 independent waves (8/CU), each
// owning 64 queries and reading K/V fragments straight from L2 (XCD-chunked
// grid keeps each (n,h,sp) slice on one XCD's L2; total L2 read 64MB ~ 2us).
// Latency hides via free-running wave TLP instead of intra-block pipelining.
__global__ __launch_bounds__(64, 2)
void k_attn(const unsigned short* __restrict__ qT,
            const unsigned short* __restrict__ kT,
            const unsigned short* __restrict__ vv,
            unsigned short* __restrict__ po, float* __restrict__ pl) {
    const int flat = blockIdx.x;
    const int orig = (flat & 7) * 256 + (flat >> 3);   // bijective on [0,2048)
    const int tw = (orig & 63) * 64;
    const int h  = (orig >> 6) & 3;
    const int z  = orig >> 8;                          // 0..7
    const int n  = z >> 2;
    const int sp = z & 3;
    const int l  = threadIdx.x;                        // 0..63
    const int r16 = l & 15, g = l >> 4;

    const size_t nh = (size_t)n * NHD + h;
    const unsigned short* qb = qT + nh * LL * CHD;
    const unsigned short* kb = kT + nh * LL * CHD;
    const unsigned short* vb = vv + nh * CHD * LL;
    const int s_beg = sp * (LL / SPLIT);   // 1024-wide slice

    // per-lane fragment source addresses
    const unsigned short* ka = kb + (size_t)(s_beg + r16) * CHD + g * 8;
    const unsigned short* va = vb + (size_t)r16 * LL + s_beg + g * 8;

    short8 ones;
    #pragma unroll
    for (int i = 0; i < 8; i++) ones[i] = (short)0x3F80;   // bf16 1.0

    short8 qf[4][2];
    #pragma unroll
    for (int qg = 0; qg < 4; qg++) {
        const unsigned short* qr = qb + (size_t)(tw + qg * 16 + r16) * CHD + g * 8;
        qf[qg][0] = *(const short8*)(qr);
        qf[qg][1] = *(const short8*)(qr + 32);
    }

    f32x4 oacc[4][4], lacc[4];
    #pragma unroll
    for (int qg = 0; qg < 4; qg++) {
        lacc[qg] = (f32x4){0.f, 0.f, 0.f, 0.f};
        #pragma unroll
        for (int cb = 0; cb < 4; cb++) oacc[qg][cb] = (f32x4){0.f, 0.f, 0.f, 0.f};
    }

    for (int it = 0; it < (LL / SPLIT) / 64; it++) {
        // ---- issue all K then V fragment loads (L2-resident) ----
        short8 kf0[4], kf1[4];
        #pragma unroll
        for (int sb = 0; sb < 4; sb++) {
            const unsigned short* kr = ka + (size_t)(it * 64 + sb * 16) * CHD;
            kf0[sb] = *(const short8*)(kr);
            kf1[sb] = *(const short8*)(kr + 32);
        }
        short8 vf0[4], vf1[4];
        #pragma unroll
        for (int cb = 0; cb < 4; cb++) {
            const unsigned short* vr = va + (size_t)cb * 16 * LL + it * 64;
            vf0[cb] = *(const short8*)(vr);
            vf1[cb] = *(const short8*)(vr + 32);
        }

        // ---- 4 independent qg streams: QKT -> exp2 -> pf ----
        short8 pf[4][2];
        #pragma unroll
        for (int qg = 0; qg < 4; qg++) {
            f32x4 sa[4];
            #pragma unroll
            for (int sb = 0; sb < 4; sb++) {
                f32x4 z4 = (f32x4){0.f, 0.f, 0.f, 0.f};
                z4 = __builtin_amdgcn_mfma_f32_16x16x32_bf16(kf0[sb], qf[qg][0], z4, 0, 0, 0);
                sa[sb] = __builtin_amdgcn_mfma_f32_16x16x32_bf16(kf1[sb], qf[qg][1], z4, 0, 0, 0);
            }
            #pragma unroll
            for (int sb = 0; sb < 4; sb++) {
                sa[sb][0] = __builtin_amdgcn_exp2f(sa[sb][0]);
                sa[sb][1] = __builtin_amdgcn_exp2f(sa[sb][1]);
                sa[sb][2] = __builtin_amdgcn_exp2f(sa[sb][2]);
                sa[sb][3] = __builtin_amdgcn_exp2f(sa[sb][3]);
            }
            pf[qg][0] = build_pf(sa[0], sa[1]);
            pf[qg][1] = build_pf(sa[2], sa[3]);
        }

        // ---- PV + lsum (MFMA pipe) ----
        #pragma unroll
        for (int cb = 0; cb < 4; cb++) {
            #pragma unroll
            for (int qg = 0; qg < 4; qg++) {
                oacc[qg][cb] = __builtin_amdgcn_mfma_f32_16x16x32_bf16(vf0[cb], pf[qg][0], oacc[qg][cb], 0, 0, 0);
                oacc[qg][cb] = __builtin_amdgcn_mfma_f32_16x16x32_bf16(vf1[cb], pf[qg][1], oacc[qg][cb], 0, 0, 0);
            }
        }
        #pragma unroll
        for (int qg = 0; qg < 4; qg++) {
            lacc[qg] = __builtin_amdgcn_mfma_f32_16x16x32_bf16(ones, pf[qg][0], lacc[qg], 0, 0, 0);
            lacc[qg] = __builtin_amdgcn_mfma_f32_16x16x32_bf16(ones, pf[qg][1], lacc[qg], 0, 0, 0);
        }
    }

    // epilogue: pl comes straight from lacc (every row = column sum)
    const size_t nhsp = ((size_t)sp * NB + n) * NHD + h;
    #pragma unroll
    for (int qg = 0; qg < 4; qg++) {
        const int t = tw + qg * 16 + r16;
        unsigned short* pob = po + ((size_t)nhsp * LL + t) * CHD;
        #pragma unroll
        for (int cb = 0; cb < 4; cb++) {
            unsigned int lo = cvtpk(oacc[qg][cb][0], oacc[qg][cb][1]);
            unsigned int hi = cvtpk(oacc[qg][cb][2], oacc[qg][cb][3]);
            *(uint2*)(pob + cb * 16 + g * 4) = make_uint2(lo, hi);
        }
        if (g == 0) pl[nhsp * LL + t] = lacc[qg][0];
    }
}

// ---------------- kernel 5: merge 4 splits -> attT bf16 [n][t][c256] ------
__global__ __launch_bounds__(256)
void k_merge(const unsigned short* __restrict__ po, const float* __restrict__ pl,
             unsigned short* __restrict__ at) {
    const int idx = blockIdx.x * 256 + threadIdx.x;   // 0 .. 131071
    const int c16 = (idx & 3) << 4;
    const int t   = (idx >> 2) & (LL - 1);
    const int nh  = idx >> 14;                        // 0..7
    float denom = 0.f;
    #pragma unroll
    for (int s = 0; s < SPLIT; s++)
        denom += pl[(size_t)(s * NB * NHD + nh) * LL + t];
    const float inv = 1.f / denom;
    float facc[16];
    #pragma unroll
    for (int k = 0; k < 16; k++) facc[k] = 0.f;
    #pragma unroll
    for (int s = 0; s < SPLIT; s++) {
        const unsigned short* pb = po + ((size_t)(s * NB * NHD + nh) * LL + t) * CHD + c16;
        short8 a = *(const short8*)(pb);
        short8 b = *(const short8*)(pb + 8);
        #pragma unroll
        for (int k = 0; k < 8; k++) {
            facc[k]     += bf2f((unsigned short)a[k]);
            facc[8 + k] += bf2f((unsigned short)b[k]);
        }
    }
    unsigned short* ob = at + ((size_t)(nh >> 2) * LL + t) * CCH + (nh & 3) * CHD + c16;
    #pragma unroll
    for (int q = 0; q < 4; q++) {
        ushort4 u;
        u.x = f2bf(facc[q * 4 + 0] * inv);
        u.y = f2bf(facc[q * 4 + 1] * inv);
        u.z = f2bf(facc[q * 4 + 2] * inv);
        u.w = f2bf(facc[q * 4 + 3] * inv);
        *(ushort4*)(ob + q * 4) = u;
    }
}

// ------- kernel 6: out projection + residual, LDS-staged at-tile ----------
__global__ __launch_bounds__(256)
void k_out(const unsigned short* __restrict__ at, const unsigned short* __restrict__ wo,
           const float* __restrict__ b_out, const float* __restrict__ x,
           float* __restrict__ out) {
    const int l0 = blockIdx.x * 64, o0 = blockIdx.y * 64, n = blockIdx.z;
    const int tid = threadIdx.x, w = tid >> 6, r16 = tid & 15, g = (tid & 63) >> 4;
    __shared__ __align__(16) unsigned short lt[64 * 256];   // 32KB
    const unsigned short* ab = at + (size_t)n * LL * CCH;

    stage_tile(lt, ab + (size_t)l0 * CCH, CCH, tid);
    __syncthreads();

    const unsigned short* wr = wo + (size_t)(o0 + w * 16 + r16) * CCH + g * 8;
    f32x4 acc[4];
    #pragma unroll
    for (int i = 0; i < 4; i++) acc[i] = (f32x4){0.f, 0.f, 0.f, 0.f};
    for (int kk = 0; kk < 8; kk++) {
        short8 wf = *(const short8*)(wr + kk * 32);
        #pragma unroll
        for (int lb = 0; lb < 4; lb++) {
            short8 xf = ldsfrag(lt, lb * 16 + r16, kk * 4 + g);
            acc[lb] = __builtin_amdgcn_mfma_f32_16x16x32_bf16(xf, wf, acc[lb], 0, 0, 0);
        }
    }
    const int o = o0 + w * 16 + r16;
    const float bb = b_out[o];
    const float* xb = x + ((size_t)n * CCH + o) * LL;
    float* ob = out + ((size_t)n * CCH + o) * LL;
    #pragma unroll
    for (int lb = 0; lb < 4; lb++) {
        const int li = l0 + lb * 16 + g * 4;
        float4 xv = *(const float4*)(xb + li);
        float4 v;
        v.x = acc[lb][0] + bb + xv.x; v.y = acc[lb][1] + bb + xv.y;
        v.z = acc[lb][2] + bb + xv.z; v.w = acc[lb][3] + bb + xv.w;
        *(float4*)(ob + li) = v;
    }
}

extern "C" void kernel_launch(void* const* d_in, const int* in_sizes, int n_in,
                              void* d_out, int out_size, void* d_ws, size_t ws_size,
                              hipStream_t stream) {
    (void)in_sizes; (void)n_in; (void)out_size; (void)ws_size;
    const float* x        = (const float*)d_in[0];
    const float* gn_scale = (const float*)d_in[1];
    const float* gn_bias  = (const float*)d_in[2];
    const float* w_qkv    = (const float*)d_in[3];
    const float* b_qkv    = (const float*)d_in[4];
    const float* w_out    = (const float*)d_in[5];
    const float* b_out    = (const float*)d_in[6];
    float* out = (float*)d_out;
    float* ws  = (float*)d_ws;
    unsigned short* wq  = (unsigned short*)(ws + OFF_WQ);
    unsigned short* wo  = (unsigned short*)(ws + OFF_WO);
    unsigned short* xt  = (unsigned short*)(ws + OFF_XT);
    unsigned short* qT  = (unsigned short*)(ws + OFF_QT);
    unsigned short* kT  = (unsigned short*)(ws + OFF_KT);
    unsigned short* vv  = (unsigned short*)(ws + OFF_V);
    unsigned short* at  = (unsigned short*)(ws + OFF_AT);
    unsigned short* po  = (unsigned short*)(ws + OFF_PO);
    float* pl = ws + OFF_L;

    k_xtgn<<<dim3(64, 4, NB), 256, 0, stream>>>(x, xt, ws);
    k_bpw<<<dim3(496), 256, 0, stream>>>(w_qkv, w_out, b_qkv, gn_scale, gn_bias, ws, wq, wo);
    k_qkv<<<dim3(64, 12, NB), 256, 0, stream>>>(wq, ws + OFF_BP, xt, qT, kT, vv);
    k_attn<<<dim3(2048), 64, 0, stream>>>(qT, kT, vv, po, pl);
    k_merge<<<dim3(512), 256, 0, stream>>>(po, pl, at);
    k_out<<<dim3(64, 4, NB), 256, 0, stream>>>(at, wo, b_out, x, out);
}

// Round 18
// 78.814 us; speedup vs baseline: 1.3618x; 1.3618x over previous
//
#include <hip/hip_runtime.h>

#define NB 2
#define CCH 256
#define LL 4096
#define NGRP 16
#define NHD 4
#define CHD 64
#define QR 768   // 3*C rows of qkv
#define SPLIT 4
#define TBLK 256 // queries per attn block (4 waves x 64)

typedef __attribute__((ext_vector_type(8))) short short8;   // 8 x bf16
typedef __attribute__((ext_vector_type(4))) float f32x4;    // MFMA acc
typedef __attribute__((ext_vector_type(4))) unsigned int uint32x4;

// ---------------- workspace layout (floats) ----------------
#define OFF_GP 64
#define OFF_BP 4224
#define OFF_WQ 5824
#define OFF_WO 202432
#define OFF_QT 235200
#define OFF_KT 1283776
#define OFF_V  2332352
#define OFF_PO 3380928
#define OFF_L  7575232
#define OFF_XT OFF_PO
#define OFF_AT OFF_QT

#define KSCALE 0.1803368801111204f   // 0.125 * log2(e)

__device__ __forceinline__ unsigned short f2bf(float f) {
    unsigned int u = __builtin_bit_cast(unsigned int, f);
    u += 0x7fffu + ((u >> 16) & 1u);   // RNE
    return (unsigned short)(u >> 16);
}
__device__ __forceinline__ float bf2f(unsigned short s) {
    unsigned int u = ((unsigned int)s) << 16;
    return __builtin_bit_cast(float, u);
}
__device__ __forceinline__ unsigned int cvtpk(float lo, float hi) {
    unsigned int r;
    asm("v_cvt_pk_bf16_f32 %0, %1, %2" : "=v"(r) : "v"(lo), "v"(hi));
    return r;
}

// Relaxed workgroup barrier (lgkmcnt only); sched_barrier stops hoisting.
__device__ __forceinline__ void barrier_lds_only() {
    asm volatile("s_waitcnt lgkmcnt(0)" ::: "memory");
    __builtin_amdgcn_s_barrier();
    __builtin_amdgcn_sched_barrier(0);
}

// Build the PV B-fragment (one 32-s half) from two QK^T accumulators
// entirely in-register (cvt_pk + permlane32/16_swap). Proven R8-R15.
__device__ __forceinline__ short8 build_pf(const f32x4 s_lo, const f32x4 s_hi) {
    unsigned int a0 = cvtpk(s_lo[0], s_lo[1]);
    unsigned int b0 = cvtpk(s_hi[0], s_hi[1]);
    unsigned int a1 = cvtpk(s_lo[2], s_lo[3]);
    unsigned int b1 = cvtpk(s_hi[2], s_hi[3]);
    asm("v_permlane32_swap_b32 %0, %1" : "+v"(a0), "+v"(b0));
    asm("v_permlane16_swap_b32 %0, %1" : "+v"(a0), "+v"(b0));
    asm("v_permlane32_swap_b32 %0, %1" : "+v"(a1), "+v"(b1));
    asm("v_permlane16_swap_b32 %0, %1" : "+v"(a1), "+v"(b1));
    uint32x4 w = {a0, a1, b0, b1};
    return __builtin_bit_cast(short8, w);
}

// XOR-swizzled 64x256 bf16 LDS tile helpers (rows of 512B = 32 16B chunks).
__device__ __forceinline__ void stage_tile(unsigned short* lt,
                                           const unsigned short* src,
                                           int srcStride, int tid) {
    #pragma unroll
    for (int p = 0; p < 4; p++) {
        const int r  = p * 16 + (tid >> 4);
        const int cb = (tid & 15) * 2;
        const unsigned short* s = src + (size_t)r * srcStride + cb * 8;
        short8 a = *(const short8*)(s);
        short8 b = *(const short8*)(s + 8);
        char* d = (char*)lt + r * 512;
        *(short8*)(d + (((cb    ) ^ (r & 15)) << 4)) = a;
        *(short8*)(d + (((cb + 1) ^ (r & 15)) << 4)) = b;
    }
}
__device__ __forceinline__ short8 ldsfrag(const unsigned short* lt, int row, int ch) {
    return *(const short8*)((const char*)lt + row * 512 + ((ch ^ (row & 15)) << 4));
}

// ------- kernel 1: x -> xT bf16 [n][l][c] + group-norm partial sums -------
__global__ __launch_bounds__(256)
void k_xtgn(const float* __restrict__ x, unsigned short* __restrict__ xt,
            float* __restrict__ ws) {
    const int l0 = blockIdx.x * 64, c0 = blockIdx.y * 64, n = blockIdx.z;
    __shared__ __align__(16) unsigned short lt[64 * 64];
    __shared__ float red[2][4][4];
    const int tid = threadIdx.x;
    const int cl = tid >> 4;
    const int ll = (tid & 15) << 2;
    float s1[4], s2[4];
    #pragma unroll
    for (int cc = 0; cc < 4; cc++) {
        const int c = cl + cc * 16;
        float4 v = *(const float4*)(x + (size_t)(n * CCH + c0 + c) * LL + l0 + ll);
        s1[cc] = (v.x + v.y) + (v.z + v.w);
        s2[cc] = (v.x * v.x + v.y * v.y) + (v.z * v.z + v.w * v.w);
        const float vv[4] = {v.x, v.y, v.z, v.w};
        #pragma unroll
        for (int j = 0; j < 4; j++) {
            const int l = ll + j;
            const int byte = l * 128 + ((((c >> 3) ^ (l & 7)) << 4) | ((c & 7) * 2));
            *(unsigned short*)((char*)lt + byte) = f2bf(vv[j]);
        }
    }
    #pragma unroll
    for (int cc = 0; cc < 4; cc++)
        #pragma unroll
        for (int off = 32; off; off >>= 1) {
            s1[cc] += __shfl_down(s1[cc], off);
            s2[cc] += __shfl_down(s2[cc], off);
        }
    if ((tid & 63) == 0) {
        const int w = tid >> 6;
        #pragma unroll
        for (int cc = 0; cc < 4; cc++) { red[0][w][cc] = s1[cc]; red[1][w][cc] = s2[cc]; }
    }
    __syncthreads();
    if (tid < 4) {
        const float a = red[0][0][tid] + red[0][1][tid] + red[0][2][tid] + red[0][3][tid];
        const float b = red[1][0][tid] + red[1][1][tid] + red[1][2][tid] + red[1][3][tid];
        const int g = n * NGRP + (c0 >> 4) + tid;
        ws[OFF_GP + (g * 64 + blockIdx.x) * 2]     = a;
        ws[OFF_GP + (g * 64 + blockIdx.x) * 2 + 1] = b;
    }
    const int lr = tid >> 2;
    const int ch = (tid & 3) << 4;
    unsigned short* dst = xt + ((size_t)n * LL + l0 + lr) * CCH + c0 + ch;
    const int b0 = lr * 128 + ((((ch >> 3)    ) ^ (lr & 7)) << 4);
    const int b1 = lr * 128 + ((((ch >> 3) + 1) ^ (lr & 7)) << 4);
    *(short8*)dst       = *(const short8*)((char*)lt + b0);
    *(short8*)(dst + 8) = *(const short8*)((char*)lt + b1);
}

// stats-from-partials preamble
__device__ __forceinline__ void load_stats(const float* __restrict__ ws,
                                           float* smu, float* srs) {
    if (threadIdx.x < 32) {
        float s1 = 0.f, s2 = 0.f;
        #pragma unroll 8
        for (int i = 0; i < 64; i++) {
            s1 += ws[OFF_GP + (threadIdx.x * 64 + i) * 2];
            s2 += ws[OFF_GP + (threadIdx.x * 64 + i) * 2 + 1];
        }
        const float inv = 1.f / (float)(16 * LL);
        float m = s1 * inv;
        float var = s2 * inv - m * m;
        smu[threadIdx.x] = m;
        srs[threadIdx.x] = rsqrtf(var + 1e-6f);
    }
    __syncthreads();
}

// ------- kernel 2: fused weight conversion + effective bias ---------------
__global__ __launch_bounds__(256)
void k_bpw(const float* __restrict__ w_qkv, const float* __restrict__ w_out,
           const float* __restrict__ b_qkv, const float* __restrict__ gn_scale,
           const float* __restrict__ gn_bias, float* __restrict__ ws,
           unsigned short* __restrict__ wq, unsigned short* __restrict__ wo) {
    __shared__ float smu[32], srs[32];
    load_stats(ws, smu, srs);
    if (blockIdx.x < 448) {
        const int e = (blockIdx.x * 256 + threadIdx.x) * 4;
        if (e < NB * QR * CCH) {
            const int n = (e >= QR * CCH) ? 1 : 0;
            const int r = e - n * QR * CCH;
            const int o = r >> 8, c = r & 255;
            float4 w  = *(const float4*)(w_qkv + (size_t)o * CCH + c);
            float4 gs = *(const float4*)(gn_scale + c);
            const float rs = srs[n * NGRP + (c >> 4)];
            const float sc = (o < 256 ? KSCALE : 1.0f) * rs;
            ushort4 u;
            u.x = f2bf(w.x * gs.x * sc); u.y = f2bf(w.y * gs.y * sc);
            u.z = f2bf(w.z * gs.z * sc); u.w = f2bf(w.w * gs.w * sc);
            *(ushort4*)(wq + (size_t)n * QR * CCH + r) = u;
        } else {
            const int r = e - NB * QR * CCH;   // < 65536
            float4 w = *(const float4*)(w_out + r);
            ushort4 u;
            u.x = f2bf(w.x); u.y = f2bf(w.y); u.z = f2bf(w.z); u.w = f2bf(w.w);
            *(ushort4*)(wo + r) = u;
        }
    } else {
        const int oi = (blockIdx.x - 448) * 32 + (threadIdx.x >> 3);  // 0..1535
        const int j  = threadIdx.x & 7;
        const int n = (oi >= QR) ? 1 : 0;
        const int o = oi - n * QR;
        const float* wr = w_qkv + (size_t)o * CCH + j * 32;
        const float* gsr = gn_scale + j * 32;
        const float* gbr = gn_bias + j * 32;
        float s = 0.f;
        #pragma unroll
        for (int c = 0; c < 32; c += 4) {
            float4 w  = *(const float4*)(wr + c);
            float4 gs = *(const float4*)(gsr + c);
            float4 gb = *(const float4*)(gbr + c);
            const int gidx = n * NGRP + ((j * 32 + c) >> 4);
            const float mu = smu[gidx], rs = srs[gidx];
            s += w.x * (gb.x - mu * rs * gs.x) + w.y * (gb.y - mu * rs * gs.y)
               + w.z * (gb.z - mu * rs * gs.z) + w.w * (gb.w - mu * rs * gs.w);
        }
        s += __shfl_down(s, 4);
        s += __shfl_down(s, 2);
        s += __shfl_down(s, 1);
        if (j == 0) ws[OFF_BP + oi] = (b_qkv[o] + s) * (o < 256 ? KSCALE : 1.0f);
    }
}

// ------- kernel 3: QKV projection, bf16 MFMA, LDS-staged shared operand ---
__global__ __launch_bounds__(256)
void k_qkv(const unsigned short* __restrict__ wq, const float* __restrict__ bp,
           const unsigned short* __restrict__ xt,
           unsigned short* __restrict__ qT, unsigned short* __restrict__ kT,
           unsigned short* __restrict__ vv) {
    const int l0 = blockIdx.x * 64, o0 = blockIdx.y * 64, n = blockIdx.z;
    const int tid = threadIdx.x, w = tid >> 6, r16 = tid & 15, g = (tid & 63) >> 4;
    __shared__ __align__(16) unsigned short lt[64 * 256];   // 32KB
    const unsigned short* xb = xt + (size_t)n * LL * CCH;
    const unsigned short* wb = wq + (size_t)n * QR * CCH;
    const bool isv = (o0 >= 512);

    stage_tile(lt, isv ? (xb + (size_t)l0 * CCH) : (wb + (size_t)o0 * CCH), CCH, tid);
    __syncthreads();

    f32x4 acc[4];
    #pragma unroll
    for (int i = 0; i < 4; i++) acc[i] = (f32x4){0.f, 0.f, 0.f, 0.f};

    if (!isv) {
        const unsigned short* xr = xb + (size_t)(l0 + w * 16 + r16) * CCH + g * 8;
        for (int kk = 0; kk < 8; kk++) {
            short8 xf = *(const short8*)(xr + kk * 32);
            #pragma unroll
            for (int af = 0; af < 4; af++) {
                short8 wf = ldsfrag(lt, af * 16 + r16, kk * 4 + g);
                acc[af] = __builtin_amdgcn_mfma_f32_16x16x32_bf16(wf, xf, acc[af], 0, 0, 0);
            }
        }
        const bool isq = (o0 < 256);
        const int h = (o0 >> 6) & 3;
        unsigned short* tb = (isq ? qT : kT) + ((size_t)n * NHD + h) * LL * CHD;
        const int t = l0 + w * 16 + r16;
        #pragma unroll
        for (int af = 0; af < 4; af++) {
            float4 bb = *(const float4*)(bp + n * QR + o0 + af * 16 + g * 4);
            ushort4 u;
            u.x = f2bf(acc[af][0] + bb.x); u.y = f2bf(acc[af][1] + bb.y);
            u.z = f2bf(acc[af][2] + bb.z); u.w = f2bf(acc[af][3] + bb.w);
            *(ushort4*)(tb + (size_t)t * CHD + af * 16 + g * 4) = u;
        }
    } else {
        const unsigned short* wr = wb + (size_t)(o0 + w * 16 + r16) * CCH + g * 8;
        for (int kk = 0; kk < 8; kk++) {
            short8 wf = *(const short8*)(wr + kk * 32);
            #pragma unroll
            for (int lb = 0; lb < 4; lb++) {
                short8 xf = ldsfrag(lt, lb * 16 + r16, kk * 4 + g);
                acc[lb] = __builtin_amdgcn_mfma_f32_16x16x32_bf16(xf, wf, acc[lb], 0, 0, 0);
            }
        }
        const int h = (o0 - 512) >> 6;
        const int o = o0 + w * 16 + r16;
        const float bb = bp[n * QR + o];
        unsigned short* vb = vv + ((size_t)n * NHD + h) * CHD * LL + (size_t)(o & 63) * LL;
        #pragma unroll
        for (int lb = 0; lb < 4; lb++) {
            ushort4 u;
            u.x = f2bf(acc[lb][0] + bb); u.y = f2bf(acc[lb][1] + bb);
            u.z = f2bf(acc[lb][2] + bb); u.w = f2bf(acc[lb][3] + bb);
            *(ushort4*)(vb + l0 + lb * 16 + g * 4) = u;
        }
    }
}

// ------- kernel 4: MFMA flash attention, 64 q/wave (R15 frontier) ---------
__global__ __launch_bounds__(256, 2)
void k_attn(const unsigned short* __restrict__ qT,
            const unsigned short* __restrict__ kT,
            const unsigned short* __restrict__ vv,
            unsigned short* __restrict__ po, float* __restrict__ pl) {
    const int t0 = blockIdx.x * TBLK;
    const int h  = blockIdx.y;
    const int n  = blockIdx.z >> 2;
    const int sp = blockIdx.z & 3;
    const int tid = threadIdx.x;
    const int w = tid >> 6, l = tid & 63, r16 = l & 15, g = l >> 4;

    const size_t nh = (size_t)n * NHD + h;
    const unsigned short* qb = qT + nh * LL * CHD;
    const unsigned short* kb = kT + nh * LL * CHD;
    const unsigned short* vb = vv + nh * CHD * LL;
    const int s_beg = sp * (LL / SPLIT);   // 1024-wide slice

    __shared__ __align__(16) unsigned short kvs[2][2][64 * 64];  // 32KB

    const int srow = tid >> 2;
    const int ss0  = (tid & 3) << 1;
    const unsigned short* ksrc = kb + (size_t)(s_beg + srow) * CHD + ss0 * 8;
    const unsigned short* vsrc = vb + (size_t)srow * LL + s_beg + ss0 * 8;
    char* base0 = (char*)&kvs[0][0][0];
    const int kd0 = srow * 128 + (((ss0    ) ^ (srow & 7)) << 4);
    const int kd1 = srow * 128 + (((ss0 + 1) ^ (srow & 7)) << 4);

    const int tw = t0 + w * 64;
    const int jk0 = ((g    ) ^ (r16 & 7)) << 4;
    const int jk1 = ((4 + g) ^ (r16 & 7)) << 4;

    short8 ones;
    #pragma unroll
    for (int i = 0; i < 8; i++) ones[i] = (short)0x3F80;   // bf16 1.0

    short8 qf[4][2];
    #pragma unroll
    for (int qg = 0; qg < 4; qg++) {
        const unsigned short* qr = qb + (size_t)(tw + qg * 16 + r16) * CHD + g * 8;
        qf[qg][0] = *(const short8*)(qr);
        qf[qg][1] = *(const short8*)(qr + 32);
    }

    f32x4 oacc[4][4], lacc[4];
    #pragma unroll
    for (int qg = 0; qg < 4; qg++) {
        lacc[qg] = (f32x4){0.f, 0.f, 0.f, 0.f};
        #pragma unroll
        for (int cb = 0; cb < 4; cb++) oacc[qg][cb] = (f32x4){0.f, 0.f, 0.f, 0.f};
    }

    const int NIT = (LL / SPLIT) / 64;   // 16

    short8 kr0 = *(const short8*)(ksrc);
    short8 kr1 = *(const short8*)(ksrc + 8);
    short8 vr0 = *(const short8*)(vsrc);
    short8 vr1 = *(const short8*)(vsrc + 8);
    *(short8*)(base0 + kd0) = kr0;
    *(short8*)(base0 + kd1) = kr1;
    *(short8*)(base0 + 8192 + kd0) = vr0;
    *(short8*)(base0 + 8192 + kd1) = vr1;
    const unsigned short* kpf = ksrc + 64 * CHD;
    const unsigned short* vpf = vsrc + 64;
    kr0 = *(const short8*)(kpf);
    kr1 = *(const short8*)(kpf + 8);
    vr0 = *(const short8*)(vpf);
    vr1 = *(const short8*)(vpf + 8);
    barrier_lds_only();

    int cur = 0;
    for (int it = 0; it < NIT; it++) {
        const char* kB = base0 + cur * 16384;
        const char* vB = kB + 8192;

        short8 kf0[4], kf1[4];
        #pragma unroll
        for (int sb = 0; sb < 4; sb++) {
            const int rb = (16 * sb + r16) * 128;
            kf0[sb] = *(const short8*)(kB + rb + jk0);
            kf1[sb] = *(const short8*)(kB + rb + jk1);
        }
        if (it + 1 < NIT) {
            char* kdn = base0 + (cur ^ 1) * 16384;
            *(short8*)(kdn + kd0) = kr0;
            *(short8*)(kdn + kd1) = kr1;
            *(short8*)(kdn + 8192 + kd0) = vr0;
            *(short8*)(kdn + 8192 + kd1) = vr1;
        }
        if (it + 2 < NIT) {
            kpf += 64 * CHD;
            vpf += 64;
            kr0 = *(const short8*)(kpf);
            kr1 = *(const short8*)(kpf + 8);
            vr0 = *(const short8*)(vpf);
            vr1 = *(const short8*)(vpf + 8);
        }

        short8 pf[4][2];
        #pragma unroll
        for (int qg = 0; qg < 4; qg++) {
            f32x4 sa[4];
            #pragma unroll
            for (int sb = 0; sb < 4; sb++) {
                f32x4 z4 = (f32x4){0.f, 0.f, 0.f, 0.f};
                z4 = __builtin_amdgcn_mfma_f32_16x16x32_bf16(kf0[sb], qf[qg][0], z4, 0, 0, 0);
                sa[sb] = __builtin_amdgcn_mfma_f32_16x16x32_bf16(kf1[sb], qf[qg][1], z4, 0, 0, 0);
            }
            #pragma unroll
            for (int sb = 0; sb < 4; sb++) {
                sa[sb][0] = __builtin_amdgcn_exp2f(sa[sb][0]);
                sa[sb][1] = __builtin_amdgcn_exp2f(sa[sb][1]);
                sa[sb][2] = __builtin_amdgcn_exp2f(sa[sb][2]);
                sa[sb][3] = __builtin_amdgcn_exp2f(sa[sb][3]);
            }
            pf[qg][0] = build_pf(sa[0], sa[1]);
            pf[qg][1] = build_pf(sa[2], sa[3]);
        }

        __builtin_amdgcn_s_setprio(1);
        #pragma unroll
        for (int cb = 0; cb < 4; cb++) {
            const int rb = (16 * cb + r16) * 128;
            short8 vf0 = *(const short8*)(vB + rb + jk0);
            short8 vf1 = *(const short8*)(vB + rb + jk1);
            #pragma unroll
            for (int qg = 0; qg < 4; qg++) {
                oacc[qg][cb] = __builtin_amdgcn_mfma_f32_16x16x32_bf16(vf0, pf[qg][0], oacc[qg][cb], 0, 0, 0);
                oacc[qg][cb] = __builtin_amdgcn_mfma_f32_16x16x32_bf16(vf1, pf[qg][1], oacc[qg][cb], 0, 0, 0);
            }
        }
        #pragma unroll
        for (int qg = 0; qg < 4; qg++) {
            lacc[qg] = __builtin_amdgcn_mfma_f32_16x16x32_bf16(ones, pf[qg][0], lacc[qg], 0, 0, 0);
            lacc[qg] = __builtin_amdgcn_mfma_f32_16x16x32_bf16(ones, pf[qg][1], lacc[qg], 0, 0, 0);
        }
        __builtin_amdgcn_s_setprio(0);

        barrier_lds_only();
        cur ^= 1;
    }

    const size_t nhsp = ((size_t)sp * NB + n) * NHD + h;
    #pragma unroll
    for (int qg = 0; qg < 4; qg++) {
        const int t = tw + qg * 16 + r16;
        unsigned short* pob = po + ((size_t)nhsp * LL + t) * CHD;
        #pragma unroll
        for (int cb = 0; cb < 4; cb++) {
            unsigned int lo = cvtpk(oacc[qg][cb][0], oacc[qg][cb][1]);
            unsigned int hi = cvtpk(oacc[qg][cb][2], oacc[qg][cb][3]);
            *(uint2*)(pob + cb * 16 + g * 4) = make_uint2(lo, hi);
        }
        if (g == 0) pl[nhsp * LL + t] = lacc[qg][0];
    }
}

// ---------------- kernel 5: merge 4 splits -> attT bf16 [n][t][c256] ------
__global__ __launch_bounds__(256)
void k_merge(const unsigned short* __restrict__ po, const float* __restrict__ pl,
             unsigned short* __restrict__ at) {
    const int idx = blockIdx.x * 256 + threadIdx.x;   // 0 .. 131071
    const int c16 = (idx & 3) << 4;
    const int t   = (idx >> 2) & (LL - 1);
    const int nh  = idx >> 14;                        // 0..7
    float denom = 0.f;
    #pragma unroll
    for (int s = 0; s < SPLIT; s++)
        denom += pl[(size_t)(s * NB * NHD + nh) * LL + t];
    const float inv = 1.f / denom;
    float facc[16];
    #pragma unroll
    for (int k = 0; k < 16; k++) facc[k] = 0.f;
    #pragma unroll
    for (int s = 0; s < SPLIT; s++) {
        const unsigned short* pb = po + ((size_t)(s * NB * NHD + nh) * LL + t) * CHD + c16;
        short8 a = *(const short8*)(pb);
        short8 b = *(const short8*)(pb + 8);
        #pragma unroll
        for (int k = 0; k < 8; k++) {
            facc[k]     += bf2f((unsigned short)a[k]);
            facc[8 + k] += bf2f((unsigned short)b[k]);
        }
    }
    unsigned short* ob = at + ((size_t)(nh >> 2) * LL + t) * CCH + (nh & 3) * CHD + c16;
    #pragma unroll
    for (int q = 0; q < 4; q++) {
        ushort4 u;
        u.x = f2bf(facc[q * 4 + 0] * inv);
        u.y = f2bf(facc[q * 4 + 1] * inv);
        u.z = f2bf(facc[q * 4 + 2] * inv);
        u.w = f2bf(facc[q * 4 + 3] * inv);
        *(ushort4*)(ob + q * 4) = u;
    }
}

// ------- kernel 6: out projection + residual, LDS-staged at-tile ----------
__global__ __launch_bounds__(256)
void k_out(const unsigned short* __restrict__ at, const unsigned short* __restrict__ wo,
           const float* __restrict__ b_out, const float* __restrict__ x,
           float* __restrict__ out) {
    const int l0 = blockIdx.x * 64, o0 = blockIdx.y * 64, n = blockIdx.z;
    const int tid = threadIdx.x, w = tid >> 6, r16 = tid & 15, g = (tid & 63) >> 4;
    __shared__ __align__(16) unsigned short lt[64 * 256];   // 32KB
    const unsigned short* ab = at + (size_t)n * LL * CCH;

    stage_tile(lt, ab + (size_t)l0 * CCH, CCH, tid);
    __syncthreads();

    const unsigned short* wr = wo + (size_t)(o0 + w * 16 + r16) * CCH + g * 8;
    f32x4 acc[4];
    #pragma unroll
    for (int i = 0; i < 4; i++) acc[i] = (f32x4){0.f, 0.f, 0.f, 0.f};
    for (int kk = 0; kk < 8; kk++) {
        short8 wf = *(const short8*)(wr + kk * 32);
        #pragma unroll
        for (int lb = 0; lb < 4; lb++) {
            short8 xf = ldsfrag(lt, lb * 16 + r16, kk * 4 + g);
            acc[lb] = __builtin_amdgcn_mfma_f32_16x16x32_bf16(xf, wf, acc[lb], 0, 0, 0);
        }
    }
    const int o = o0 + w * 16 + r16;
    const float bb = b_out[o];
    const float* xb = x + ((size_t)n * CCH + o) * LL;
    float* ob = out + ((size_t)n * CCH + o) * LL;
    #pragma unroll
    for (int lb = 0; lb < 4; lb++) {
        const int li = l0 + lb * 16 + g * 4;
        float4 xv = *(const float4*)(xb + li);
        float4 v;
        v.x = acc[lb][0] + bb + xv.x; v.y = acc[lb][1] + bb + xv.y;
        v.z = acc[lb][2] + bb + xv.z; v.w = acc[lb][3] + bb + xv.w;
        *(float4*)(ob + li) = v;
    }
}

extern "C" void kernel_launch(void* const* d_in, const int* in_sizes, int n_in,
                              void* d_out, int out_size, void* d_ws, size_t ws_size,
                              hipStream_t stream) {
    (void)in_sizes; (void)n_in; (void)out_size; (void)ws_size;
    const float* x        = (const float*)d_in[0];
    const float* gn_scale = (const float*)d_in[1];
    const float* gn_bias  = (const float*)d_in[2];
    const float* w_qkv    = (const float*)d_in[3];
    const float* b_qkv    = (const float*)d_in[4];
    const float* w_out    = (const float*)d_in[5];
    const float* b_out    = (const float*)d_in[6];
    float* out = (float*)d_out;
    float* ws  = (float*)d_ws;
    unsigned short* wq  = (unsigned short*)(ws + OFF_WQ);
    unsigned short* wo  = (unsigned short*)(ws + OFF_WO);
    unsigned short* xt  = (unsigned short*)(ws + OFF_XT);
    unsigned short* qT  = (unsigned short*)(ws + OFF_QT);
    unsigned short* kT  = (unsigned short*)(ws + OFF_KT);
    unsigned short* vv  = (unsigned short*)(ws + OFF_V);
    unsigned short* at  = (unsigned short*)(ws + OFF_AT);
    unsigned short* po  = (unsigned short*)(ws + OFF_PO);
    float* pl = ws + OFF_L;

    k_xtgn<<<dim3(64, 4, NB), 256, 0, stream>>>(x, xt, ws);
    k_bpw<<<dim3(496), 256, 0, stream>>>(w_qkv, w_out, b_qkv, gn_scale, gn_bias, ws, wq, wo);
    k_qkv<<<dim3(64, 12, NB), 256, 0, stream>>>(wq, ws + OFF_BP, xt, qT, kT, vv);
    k_attn<<<dim3(LL / TBLK, NHD, NB * SPLIT), 256, 0, stream>>>(qT, kT, vv, po, pl);
    k_merge<<<dim3(512), 256, 0, stream>>>(po, pl, at);
    k_out<<<dim3(64, 4, NB), 256, 0, stream>>>(at, wo, b_out, x, out);
}